// Round 10
// baseline (5230.690 us; speedup 1.0000x reference)
//
#include <hip/hip_runtime.h>
#include <stdint.h>

#define T_ 1024
#define B_ 64
#define I_ 256
#define H_ 512
#define O_ 5
#define NCHAIN 8
#define NB 8             // batches per chain
#define GRID_MAIN 256    // 8 chains x 32 WGs; wave = independent unit (4 j, full K)
#define BLOCK_MAIN 256
#define EX_OFF 4096      // ex offset in ws (bytes); flags occupy [0,4096)
#define BH (B_*H_)
#define TBO (T_*B_*O_)

typedef __bf16 bf16x8 __attribute__((ext_vector_type(8)));
typedef float floatx4 __attribute__((ext_vector_type(4)));
typedef unsigned short u16;
typedef unsigned int u32;
typedef u32 u32x2 __attribute__((ext_vector_type(2)));
typedef u32 u32x4 __attribute__((ext_vector_type(4)));

__device__ __forceinline__ u16 f2bf(float f) {
  unsigned int u = __float_as_uint(f);
  u += 0x7fffu + ((u >> 16) & 1u);   // RNE
  return (u16)(u >> 16);
}
__device__ __forceinline__ float bf2f(u16 v) {
  return __uint_as_float(((unsigned int)v) << 16);
}
__device__ __forceinline__ float sigmoid_f(float x) {
  return 1.0f / (1.0f + __expf(-x));
}
__device__ __forceinline__ float tanh_f(float x) {
  return 2.0f / (1.0f + __expf(-2.0f * x)) - 1.0f;
}

// ---- L3-coherent primitives (sc0 sc1 = bypass L1/L2; Infinity Cache is the
// coherence point). Flag-then-payload protocol — best of R2..R9 (payload lines
// touched exactly once; polls on separate tiny flag lines).
__device__ __forceinline__ void store_u32_l3(u32* p, u32 v) {
  asm volatile("global_store_dword %0, %1, off sc0 sc1" :: "v"(p), "v"(v) : "memory");
}
__device__ __forceinline__ void store_u16_l3(u16* p, u16 v) {
  u32 vv = v;
  asm volatile("global_store_short %0, %1, off sc0 sc1" :: "v"(p), "v"(vv) : "memory");
}
__device__ __forceinline__ u32x2 load_flag2(const u32* p) {
  u32x2 v;
  asm volatile("global_load_dwordx2 %0, %1, off sc0 sc1\n\ts_waitcnt vmcnt(0)"
               : "=&v"(v) : "v"(p) : "memory");
  return v;
}
// 16-chunk bulk h payload (bf16 u16 ex; one K-chunk = 64 B/batch-row), ONE vmcnt.
__device__ __forceinline__ void load_h16(const u16* p, u32x4* r) {
  asm volatile(
    "global_load_dwordx4 %0, %16, off sc0 sc1\n\t"
    "global_load_dwordx4 %1, %16, off offset:64 sc0 sc1\n\t"
    "global_load_dwordx4 %2, %16, off offset:128 sc0 sc1\n\t"
    "global_load_dwordx4 %3, %16, off offset:192 sc0 sc1\n\t"
    "global_load_dwordx4 %4, %16, off offset:256 sc0 sc1\n\t"
    "global_load_dwordx4 %5, %16, off offset:320 sc0 sc1\n\t"
    "global_load_dwordx4 %6, %16, off offset:384 sc0 sc1\n\t"
    "global_load_dwordx4 %7, %16, off offset:448 sc0 sc1\n\t"
    "global_load_dwordx4 %8, %16, off offset:512 sc0 sc1\n\t"
    "global_load_dwordx4 %9, %16, off offset:576 sc0 sc1\n\t"
    "global_load_dwordx4 %10, %16, off offset:640 sc0 sc1\n\t"
    "global_load_dwordx4 %11, %16, off offset:704 sc0 sc1\n\t"
    "global_load_dwordx4 %12, %16, off offset:768 sc0 sc1\n\t"
    "global_load_dwordx4 %13, %16, off offset:832 sc0 sc1\n\t"
    "global_load_dwordx4 %14, %16, off offset:896 sc0 sc1\n\t"
    "global_load_dwordx4 %15, %16, off offset:960 sc0 sc1\n\t"
    "s_waitcnt vmcnt(0)"
    : "=&v"(r[0]), "=&v"(r[1]), "=&v"(r[2]), "=&v"(r[3]),
      "=&v"(r[4]), "=&v"(r[5]), "=&v"(r[6]), "=&v"(r[7]),
      "=&v"(r[8]), "=&v"(r[9]), "=&v"(r[10]), "=&v"(r[11]),
      "=&v"(r[12]), "=&v"(r[13]), "=&v"(r[14]), "=&v"(r[15])
    : "v"(p) : "memory");
}

// Persistent LSTM, 8 chains x 128 independent WAVES (32 WGs x 4). Each wave:
// 4 hidden units (jj packed with the 4 gates into MFMA m-rows: m = 4*g + jj),
// full K = 768, 8 batches. ZERO __syncthreads in the t-loop — no cross-wave
// reduction, no part[] LDS, no x staging barrier (x loaded directly, cached —
// read-only data, so L1/L2 are legal). Exchange: per-wave flag after vmcnt
// drain; consumer polls 128 flags via one dwordx2/lane, then ONE bulk payload.
__global__ __launch_bounds__(BLOCK_MAIN, 1)
void lstm_persistent(const float* __restrict__ x,
                     const float* __restrict__ W_ih,
                     const float* __restrict__ W_hh,
                     const float* __restrict__ b_ih,
                     const float* __restrict__ b_hh,
                     float* __restrict__ out,
                     u32* __restrict__ flags,   // [8][128]
                     u16* __restrict__ ex,      // [2][B_][H_] bf16
                     u16* __restrict__ hist)    // [(T_+1)][B_][H_] bf16
{
  __shared__ float scr[4][16 * 20];   // per-wave transpose scratch (no barrier)

  const int tid   = threadIdx.x;
  const int wg    = blockIdx.x;
  const int w     = tid >> 6;                  // wave in WG
  const int lane  = tid & 63;
  const int q     = lane >> 4;
  const int n     = lane & 15;
  const int chain = wg & 7;
  const int wid   = (wg >> 3) * 4 + w;         // wave id in chain [0,128)
  const int jb    = (wg >> 3) * 16 + w * 4;    // this wave's 4 j's: jb..jb+3
  const int bbase = chain * NB;

  // ---- W -> A-fragments, m-row = 4*g + jj : row m=n -> g=n>>2, jj=n&3 ----
  bf16x8 afrag[24];
  {
    const int g  = n >> 2;
    const int jj = n & 3;
    const int row = g * H_ + jb + jj;
    #pragma unroll
    for (int kc = 0; kc < 24; ++kc) {
      const float* src = (kc < 8)
          ? W_ih + (size_t)row * I_ + kc * 32 + q * 8
          : W_hh + (size_t)row * H_ + (kc - 8) * 32 + q * 8;
      float4 f0 = ((const float4*)src)[0];
      float4 f1 = ((const float4*)src)[1];
      bf16x8 a;
      a[0]=(__bf16)f0.x; a[1]=(__bf16)f0.y; a[2]=(__bf16)f0.z; a[3]=(__bf16)f0.w;
      a[4]=(__bf16)f1.x; a[5]=(__bf16)f1.y; a[6]=(__bf16)f1.z; a[7]=(__bf16)f1.w;
      afrag[kc] = a;
    }
  }

  // ---- elementwise identity: lane (q, n<8) owns (j = jb + q, b = bbase + n) ----
  float bias4[4];
  #pragma unroll
  for (int g = 0; g < 4; ++g)
    bias4[g] = b_ih[g * H_ + jb + q] + b_hh[g * H_ + jb + q];
  float cval = 0.0f;

  u32* myflags = flags + chain * 128;
  const u32* fp = myflags + lane * 2;          // 64 lanes cover 128 flags
  const u16* hpbase = ex + (size_t)(bbase + (n & 7)) * H_ + q * 8;

  // ---- prologue: x_0 fragments ----
  bf16x8 xfrag[8];
  {
    const float* xs = x + (size_t)(bbase + (n & 7)) * I_;
    #pragma unroll
    for (int kc = 0; kc < 8; ++kc) {
      float4 f0 = ((const float4*)(xs + kc * 32 + q * 8))[0];
      float4 f1 = ((const float4*)(xs + kc * 32 + q * 8))[1];
      bf16x8 a;
      a[0]=(__bf16)f0.x; a[1]=(__bf16)f0.y; a[2]=(__bf16)f0.z; a[3]=(__bf16)f0.w;
      a[4]=(__bf16)f1.x; a[5]=(__bf16)f1.y; a[6]=(__bf16)f1.z; a[7]=(__bf16)f1.w;
      xfrag[kc] = a;
    }
  }

  for (int t = 0; t < T_; ++t) {
    const int sr = t & 1, sw = (t + 1) & 1;

    // ---- poll: all 128 producer-wave flags >= t (2 flags/lane, 1 RT/iter) ----
    for (;;) {
      u32x2 f = load_flag2(fp);
      if (__all((int)(f[0] >= (u32)t && f[1] >= (u32)t))) break;
    }

    // ---- bulk h payload: 16 K-chunks, one vmcnt ----
    u32x4 r[16];
    load_h16(hpbase + (size_t)sr * BH, r);

    // ---- MFMA: two independent accumulator chains (x, h) ----
    floatx4 ax = {}, ah = {};
    #pragma unroll
    for (int kc = 0; kc < 8; ++kc)
      ax = __builtin_amdgcn_mfma_f32_16x16x32_bf16(afrag[kc], xfrag[kc], ax, 0, 0, 0);
    #pragma unroll
    for (int hk = 0; hk < 16; ++hk)
      ah = __builtin_amdgcn_mfma_f32_16x16x32_bf16(afrag[8 + hk],
            __builtin_bit_cast(bf16x8, r[hk]), ah, 0, 0, 0);

    // ---- issue x_{t+1} loads now (cached; drained by pre-flag vmcnt) ----
    float4 xr[8][2];
    {
      const int ts = (t + 1 < T_) ? (t + 1) : (T_ - 1);
      const float* xs = x + ((size_t)ts * B_ + bbase + (n & 7)) * I_;
      #pragma unroll
      for (int kc = 0; kc < 8; ++kc) {
        xr[kc][0] = ((const float4*)(xs + kc * 32 + q * 8))[0];
        xr[kc][1] = ((const float4*)(xs + kc * 32 + q * 8))[1];
      }
    }

    // ---- per-wave transpose: lane(q,n) holds C rows m=q*4+r (g=q, jj=r) ----
    // write [col n][m] then read m = 4g + q for own jj=q. stride 20: b128-aligned,
    // conflict-free reads.
    {
      float4 s;
      s.x = ax[0] + ah[0]; s.y = ax[1] + ah[1];
      s.z = ax[2] + ah[2]; s.w = ax[3] + ah[3];
      *(float4*)&scr[w][n * 20 + q * 4] = s;
    }
    float gate[4];
    #pragma unroll
    for (int g = 0; g < 4; ++g)
      gate[g] = scr[w][n * 20 + g * 4 + q] + bias4[g];

    // ---- elementwise + publish (lanes n<8; j = jb+q, b = bbase+n) ----
    const float ig = sigmoid_f(gate[0]);
    const float fg = sigmoid_f(gate[1]);
    const float gg = tanh_f(gate[2]);
    const float og = sigmoid_f(gate[3]);
    cval = fg * cval + ig * gg;
    const float hval = og * tanh_f(cval);
    if (n < 8) {
      const int bg = bbase + n;
      const int jg = jb + q;
      const u16 hb = f2bf(hval);
      store_u16_l3(ex + (size_t)sw * BH + (size_t)bg * H_ + jg, hb);
      hist[(size_t)(t + 1) * BH + (size_t)bg * H_ + jg] = hb;
      if (t == T_ - 1) {
        out[TBO + (size_t)bg * H_ + jg]      = hval;   // h_T
        out[TBO + BH + (size_t)bg * H_ + jg] = cval;   // c_T
      }
    }

    // ---- drain (h stores + x loads) then per-wave flag ----
    asm volatile("s_waitcnt vmcnt(0)" ::: "memory");
    if (lane == 0)
      store_u32_l3(&myflags[wid], (u32)(t + 1));

    // ---- convert x_{t+1} (data already drained) ----
    #pragma unroll
    for (int kc = 0; kc < 8; ++kc) {
      bf16x8 a;
      a[0]=(__bf16)xr[kc][0].x; a[1]=(__bf16)xr[kc][0].y;
      a[2]=(__bf16)xr[kc][0].z; a[3]=(__bf16)xr[kc][0].w;
      a[4]=(__bf16)xr[kc][1].x; a[5]=(__bf16)xr[kc][1].y;
      a[6]=(__bf16)xr[kc][1].z; a[7]=(__bf16)xr[kc][1].w;
      xfrag[kc] = a;
    }
  }
}

// outputs[t,b,:] = h_t @ fc_w^T + fc_b ; one wave per (t,b) row
__global__ __launch_bounds__(256)
void fc_kernel(const u16* __restrict__ hist,
               const float* __restrict__ fc_w,
               const float* __restrict__ fc_b,
               float* __restrict__ out)
{
  typedef unsigned short u16x8v __attribute__((ext_vector_type(8)));
  const int gw   = (blockIdx.x * 256 + threadIdx.x) >> 6;
  const int lane = threadIdx.x & 63;
  const int t = gw >> 6;
  const int b = gw & 63;
  const u16* hrow = hist + ((size_t)(t + 1) * B_ + b) * H_ + lane * 8;
  uint4 hv = *(const uint4*)hrow;
  float h[8];
  {
    u16x8v hu = __builtin_bit_cast(u16x8v, hv);
    #pragma unroll
    for (int i = 0; i < 8; ++i) h[i] = bf2f(hu[i]);
  }
  float accs[O_];
  #pragma unroll
  for (int o = 0; o < O_; ++o) {
    const float* wr = fc_w + (size_t)o * H_ + lane * 8;
    float4 w0 = ((const float4*)wr)[0];
    float4 w1 = ((const float4*)wr)[1];
    accs[o] = h[0]*w0.x + h[1]*w0.y + h[2]*w0.z + h[3]*w0.w
            + h[4]*w1.x + h[5]*w1.y + h[6]*w1.z + h[7]*w1.w;
  }
  #pragma unroll
  for (int o = 0; o < O_; ++o)
    #pragma unroll
    for (int off = 32; off > 0; off >>= 1)
      accs[o] += __shfl_down(accs[o], off, 64);
  if (lane == 0) {
    #pragma unroll
    for (int o = 0; o < O_; ++o)
      out[((size_t)t * B_ + b) * O_ + o] = accs[o] + fc_b[o];
  }
}

extern "C" void kernel_launch(void* const* d_in, const int* in_sizes, int n_in,
                              void* d_out, int out_size, void* d_ws, size_t ws_size,
                              hipStream_t stream)
{
  (void)in_sizes; (void)n_in; (void)out_size; (void)ws_size;
  const float* x    = (const float*)d_in[0];
  const float* W_ih = (const float*)d_in[1];
  const float* W_hh = (const float*)d_in[2];
  const float* b_ih = (const float*)d_in[3];
  const float* b_hh = (const float*)d_in[4];
  const float* fc_w = (const float*)d_in[5];
  const float* fc_b = (const float*)d_in[6];
  float* out = (float*)d_out;

  u32* flags = (u32*)d_ws;                              // [8][128] = 4 KB
  u16* ex    = (u16*)((char*)d_ws + EX_OFF);            // [2][B][H] u16 = 128 KB
  u16* hist  = (u16*)((char*)d_ws + EX_OFF + 2 * BH * 2);

  // zero flags + both ex slots (slot0 = h_0 = 0; clears 0xAA poison)
  hipMemsetAsync(d_ws, 0, EX_OFF + 2 * BH * 2, stream);

  lstm_persistent<<<GRID_MAIN, BLOCK_MAIN, 0, stream>>>(
      x, W_ih, W_hh, b_ih, b_hh, out, flags, ex, hist);
  fc_kernel<<<(T_ * B_) / 4, 256, 0, stream>>>(hist, fc_w, fc_b, out);
}

// Round 11
// 4624.412 us; speedup vs baseline: 1.1311x; 1.1311x over previous
//
#include <hip/hip_runtime.h>
#include <stdint.h>

#define T_ 1024
#define B_ 64
#define I_ 256
#define H_ 512
#define O_ 5
#define NCHAIN 8
#define NB 8             // batches per chain
#define JW 16            // hidden columns per WG
#define GRID_MAIN 256    // 8 chains x 32 WGs (chain = wg&7, jslot = wg>>3)
#define BLOCK_MAIN 256
#define XBS 264          // xbuf row stride in u16 (R7 value — R9's 266 regressed)
#define EX_OFF 4096      // ex offset in ws (bytes)
#define BH (B_*H_)
#define TBO (T_*B_*O_)

typedef __bf16 bf16x8 __attribute__((ext_vector_type(8)));
typedef float floatx4 __attribute__((ext_vector_type(4)));
typedef unsigned short u16;
typedef unsigned short u16x8 __attribute__((ext_vector_type(8)));
typedef unsigned int u32;
typedef unsigned long long u64;
typedef u32 u32x4 __attribute__((ext_vector_type(4)));

__device__ __forceinline__ u16 f2bf(float f) {
  unsigned int u = __float_as_uint(f);
  u += 0x7fffu + ((u >> 16) & 1u);   // RNE
  return (u16)(u >> 16);
}
__device__ __forceinline__ float bf2f(u16 v) {
  return __uint_as_float(((unsigned int)v) << 16);
}
__device__ __forceinline__ float sigmoid_f(float x) {
  return 1.0f / (1.0f + __expf(-x));
}
__device__ __forceinline__ float tanh_f(float x) {
  return 2.0f / (1.0f + __expf(-2.0f * x)) - 1.0f;
}

// ---- L3-coherent primitives (sc0 sc1 = bypass L1/L2; Infinity Cache is the
// coherence point). Protocol: HINT flags (no producer drain) + TAG-validated
// payload read exactly once in the common case.
__device__ __forceinline__ void store_u32_l3(u32* p, u32 v) {
  asm volatile("global_store_dword %0, %1, off sc0 sc1" :: "v"(p), "v"(v) : "memory");
}
__device__ __forceinline__ void store_u64_l3(u64* p, u64 v) {
  asm volatile("global_store_dwordx2 %0, %1, off sc0 sc1" :: "v"(p), "v"(v) : "memory");
}
__device__ __forceinline__ u32 load_u32_l3(const u32* p) {
  u32 v;
  asm volatile("global_load_dword %0, %1, off sc0 sc1\n\ts_waitcnt vmcnt(0)"
               : "=v"(v) : "v"(p) : "memory");
  return v;
}

// Tagged payload bulk loads (u32 per h = tag16|bf16; chunk of 32 h = 128 B per
// batch row; per-lane slice = 2 dwordx4 per chunk at +0/+16). ONE vmcnt.
#define T8_BODY \
    "global_load_dwordx4 %0, %8, off sc0 sc1\n\t" \
    "global_load_dwordx4 %1, %8, off offset:16 sc0 sc1\n\t" \
    "global_load_dwordx4 %2, %8, off offset:128 sc0 sc1\n\t" \
    "global_load_dwordx4 %3, %8, off offset:144 sc0 sc1\n\t" \
    "global_load_dwordx4 %4, %8, off offset:256 sc0 sc1\n\t" \
    "global_load_dwordx4 %5, %8, off offset:272 sc0 sc1\n\t" \
    "global_load_dwordx4 %6, %8, off offset:384 sc0 sc1\n\t" \
    "global_load_dwordx4 %7, %8, off offset:400 sc0 sc1\n\t" \
    "s_waitcnt vmcnt(0)"
__device__ __forceinline__ void load_t8(const u32* p, u32x4* r) {
  asm volatile(T8_BODY
    : "=&v"(r[0]), "=&v"(r[1]), "=&v"(r[2]), "=&v"(r[3]),
      "=&v"(r[4]), "=&v"(r[5]), "=&v"(r[6]), "=&v"(r[7])
    : "v"(p) : "memory");
}
#define T12_BODY \
    "global_load_dwordx4 %0, %12, off sc0 sc1\n\t" \
    "global_load_dwordx4 %1, %12, off offset:16 sc0 sc1\n\t" \
    "global_load_dwordx4 %2, %12, off offset:128 sc0 sc1\n\t" \
    "global_load_dwordx4 %3, %12, off offset:144 sc0 sc1\n\t" \
    "global_load_dwordx4 %4, %12, off offset:256 sc0 sc1\n\t" \
    "global_load_dwordx4 %5, %12, off offset:272 sc0 sc1\n\t" \
    "global_load_dwordx4 %6, %12, off offset:384 sc0 sc1\n\t" \
    "global_load_dwordx4 %7, %12, off offset:400 sc0 sc1\n\t" \
    "global_load_dwordx4 %8, %12, off offset:512 sc0 sc1\n\t" \
    "global_load_dwordx4 %9, %12, off offset:528 sc0 sc1\n\t" \
    "global_load_dwordx4 %10, %12, off offset:640 sc0 sc1\n\t" \
    "global_load_dwordx4 %11, %12, off offset:656 sc0 sc1\n\t" \
    "s_waitcnt vmcnt(0)"
__device__ __forceinline__ void load_t12(const u32* p, u32x4* r) {
  asm volatile(T12_BODY
    : "=&v"(r[0]), "=&v"(r[1]), "=&v"(r[2]), "=&v"(r[3]), "=&v"(r[4]), "=&v"(r[5]),
      "=&v"(r[6]), "=&v"(r[7]), "=&v"(r[8]), "=&v"(r[9]), "=&v"(r[10]), "=&v"(r[11])
    : "v"(p) : "memory");
}

// stage bf16(x[ts]) slice (8 batches x 256) into LDS xbuf slot; u in [0,128)
__device__ __forceinline__ void stage_x(const float* __restrict__ xsrc,
                                        u16 (*xb)[XBS], int u) {
  #pragma unroll
  for (int i = 0; i < 2; ++i) {
    int cid = u + 128 * i;          // 256 chunks of 8 floats
    int b  = cid >> 5;
    int ko = (cid & 31) * 8;
    const float4* s = (const float4*)(xsrc + (size_t)b * I_ + ko);
    float4 f0 = s[0], f1 = s[1];
    u16x8 uu;
    uu[0]=f2bf(f0.x); uu[1]=f2bf(f0.y); uu[2]=f2bf(f0.z); uu[3]=f2bf(f0.w);
    uu[4]=f2bf(f1.x); uu[5]=f2bf(f1.y); uu[6]=f2bf(f1.z); uu[7]=f2bf(f1.w);
    *(u16x8*)&xb[b][ko] = uu;
  }
}

// Persistent LSTM, 8 chains x 32 WGs (R7 structure). Publish path is DRAIN-FREE:
// producer waves 0,1 store tagged h words ((t+1)<<16|bf16) then their per-wave
// hint flag immediately (no s_waitcnt). Consumer: R7's cheap flag poll on
// separate lines (no payload-line contention — R8's failure mode), then ONE
// bulk payload read validated by the embedded tags; rare re-read if the flag
// outran the h stores. Tags also make slot-reuse races self-correcting.
__global__ __launch_bounds__(BLOCK_MAIN, 1)
void lstm_persistent(const float* __restrict__ x,
                     const float* __restrict__ W_ih,
                     const float* __restrict__ W_hh,
                     const float* __restrict__ b_ih,
                     const float* __restrict__ b_hh,
                     float* __restrict__ out,
                     u32* __restrict__ flags,   // [8][64]: 2 per producer WG
                     u32* __restrict__ ex,      // [2][B_][H_] tagged u32
                     u16* __restrict__ hist)    // [(T_+1)][B_][H_] bf16
{
  __shared__ __align__(16) u16 xbuf[2][NB][XBS];
  __shared__ float part[4 * 4 * 16 * 17];       // [w][gate][j16][col(+pad)]

  const int tid  = threadIdx.x;
  const int wg   = blockIdx.x;
  const int w    = tid >> 6;        // wave id = K-quarter
  const int lane = tid & 63;
  const int q    = lane >> 4;
  const int n    = lane & 15;
  const int chain = wg & 7;
  const int jslot = wg >> 3;
  const int jbase = jslot * JW;
  const int bbase = chain * NB;

  // ---- W -> register A-fragments (A[m=lane&15][k=q*8+i]), once ----
  bf16x8 afrag[4][6];
  #pragma unroll
  for (int g = 0; g < 4; ++g) {
    #pragma unroll
    for (int kk = 0; kk < 6; ++kk) {
      const int kc  = w * 6 + kk;                 // K-chunk of 32
      const int row = g * H_ + jbase + n;         // gate row in [0,2048)
      const float* src;
      if (kc < 8) src = W_ih + (size_t)row * I_ + kc * 32 + q * 8;
      else        src = W_hh + (size_t)row * H_ + (kc - 8) * 32 + q * 8;
      float4 f0 = ((const float4*)src)[0];
      float4 f1 = ((const float4*)src)[1];
      bf16x8 a;
      a[0]=(__bf16)f0.x; a[1]=(__bf16)f0.y; a[2]=(__bf16)f0.z; a[3]=(__bf16)f0.w;
      a[4]=(__bf16)f1.x; a[5]=(__bf16)f1.y; a[6]=(__bf16)f1.z; a[7]=(__bf16)f1.w;
      afrag[g][kk] = a;
    }
  }

  // ---- elementwise identity: threads 0..127 own (eb in [0,8), ej in [0,16)) ----
  const int eb = tid >> 4;
  const int ej = tid & 15;
  float bias[4];
  float cval = 0.0f;
  if (tid < 128) {
    #pragma unroll
    for (int g = 0; g < 4; ++g)
      bias[g] = b_ih[g * H_ + jbase + ej] + b_hh[g * H_ + jbase + ej];
  }

  const int nx   = (w == 0) ? 6 : ((w == 1) ? 2 : 0);
  const int hoff = (w == 2) ? 128 : ((w == 3) ? 320 : 0);  // first h j-index
  // hint-flag subset: 2 flags per producer WG; wave needs jslots covering its
  // h K-slice: w1 -> jslots 0-7 (flags 0-15), w2 -> 8-19 (16-39), w3 -> 20-31 (40-63)
  const int fbase = (w == 2) ? 16 : ((w == 3) ? 40 : 0);
  const int fcnt  = (w == 1) ? 16 : 24;
  u32* myflags = flags + chain * 64;
  const u32* fp = myflags + fbase + (lane % fcnt);
  const u32* hp0 = ex + (size_t)(bbase + (n & 7)) * H_ + hoff + q * 8;
  const u32* hp1 = hp0 + BH;

  // ---- pre-stage x_0 ----
  if (tid >= 128) stage_x(x + (size_t)bbase * I_, xbuf[0], tid - 128);
  __syncthreads();

  for (int t = 0; t < T_; ++t) {
    const int sr = t & 1, sw = (t + 1) & 1;

    bf16x8 bfrag[6];
    #pragma unroll
    for (int kk = 0; kk < 6; ++kk)
      if (kk < nx)
        bfrag[kk] = __builtin_bit_cast(bf16x8,
            *(const uint4*)&xbuf[sr][n & 7][(w * 6 + kk) * 32 + q * 8]);

    if (w > 0) {
      // ---- hint-flag poll (separate tiny lines; 1 dword/lane) ----
      for (;;) {
        u32 f = load_u32_l3(fp);
        if (__all((int)(f >= (u32)t))) break;
        __builtin_amdgcn_s_sleep(1);
      }
      // ---- ONE bulk tagged payload read; re-read only if flag outran h ----
      const u32 tp = (u32)t << 16;
      const u32* hp = sr ? hp1 : hp0;
      u32x4 r[12];
      for (;;) {
        if (w == 1) load_t8(hp, r); else load_t12(hp, r);
        u32 bad = 0;
        #pragma unroll
        for (int i = 0; i < 12; ++i) {
          if (i < ((w == 1) ? 8 : 12)) {
            u32x4 v = r[i];
            bad |= (v[0] ^ tp) | (v[1] ^ tp) | (v[2] ^ tp) | (v[3] ^ tp);
          }
        }
        bad &= 0xFFFF0000u;
        if (!__any((int)(bad != 0u))) break;
        __builtin_amdgcn_s_sleep(1);
      }
      // unpack tagged words -> bf16 B-fragments
      #pragma unroll
      for (int kk = 0; kk < 6; ++kk) {
        if (kk >= nx) {
          const int ii = (kk - nx) * 2;
          u32x4 a = r[ii], b = r[ii + 1];
          u32x4 pk;
          pk[0] = (a[0] & 0xFFFFu) | (a[1] << 16);
          pk[1] = (a[2] & 0xFFFFu) | (a[3] << 16);
          pk[2] = (b[0] & 0xFFFFu) | (b[1] << 16);
          pk[3] = (b[2] & 0xFFFFu) | (b[3] << 16);
          bfrag[kk] = __builtin_bit_cast(bf16x8, pk);
        }
      }
    }

    // ---- MFMA partial gates over this wave's K-quarter ----
    floatx4 acc[4] = {};
    #pragma unroll
    for (int kk = 0; kk < 6; ++kk) {
      #pragma unroll
      for (int g = 0; g < 4; ++g)
        acc[g] = __builtin_amdgcn_mfma_f32_16x16x32_bf16(afrag[g][kk], bfrag[kk], acc[g], 0, 0, 0);
    }

    // write partial C tiles (C: col=lane&15=batch, row=q*4+reg=j)
    #pragma unroll
    for (int g = 0; g < 4; ++g)
      #pragma unroll
      for (int r = 0; r < 4; ++r)
        part[((w * 4 + g) * 16 + (q * 4 + r)) * 17 + n] = acc[g][r];
    __syncthreads();

    if (tid < 128) {
      // ---- reduce 4 K-partials, gates -> c,h ; tagged publish + hint flag ----
      float gate[4];
      #pragma unroll
      for (int g = 0; g < 4; ++g) {
        float s = bias[g];
        #pragma unroll
        for (int w2 = 0; w2 < 4; ++w2)
          s += part[((w2 * 4 + g) * 16 + ej) * 17 + eb];
        gate[g] = s;
      }
      const float ig = sigmoid_f(gate[0]);
      const float fg = sigmoid_f(gate[1]);
      const float gg = tanh_f(gate[2]);
      const float og = sigmoid_f(gate[3]);
      cval = fg * cval + ig * gg;
      const float hval = og * tanh_f(cval);
      const int bg = bbase + eb;
      const int jg = jbase + ej;
      const u32 tagged = ((u32)(t + 1) << 16) | (u32)f2bf(hval);
      const u32 other = __shfl_xor((int)tagged, 1, 64);
      if ((tid & 1) == 0) {
        // pair of tagged words as one u64 store
        store_u64_l3((u64*)(ex + (size_t)sw * BH + (size_t)bg * H_ + jg),
                     ((u64)other << 32) | (u64)tagged);
        *(u32*)(hist + (size_t)(t + 1) * BH + (size_t)bg * H_ + jg) =
            (tagged & 0xFFFFu) | (other << 16);
      }
      // per-wave hint flag, NO drain (tags are ground truth)
      if (lane == 0)
        store_u32_l3(&myflags[jslot * 2 + w], (u32)(t + 1));
      if (t == T_ - 1) {
        out[TBO + (size_t)bg * H_ + jg]      = hval;   // h_T
        out[TBO + BH + (size_t)bg * H_ + jg] = cval;   // c_T
      }
    } else {
      // ---- waves 2,3: pre-stage x_{t+1} ----
      const int ts = (t + 1 < T_) ? (t + 1) : (T_ - 1);
      stage_x(x + ((size_t)ts * B_ + bbase) * I_, xbuf[sw], tid - 128);
    }
    __syncthreads();   // xbuf/part WAR only — publish already done
  }
}

// outputs[t,b,:] = h_t @ fc_w^T + fc_b ; one wave per (t,b) row
__global__ __launch_bounds__(256)
void fc_kernel(const u16* __restrict__ hist,
               const float* __restrict__ fc_w,
               const float* __restrict__ fc_b,
               float* __restrict__ out)
{
  const int gw   = (blockIdx.x * 256 + threadIdx.x) >> 6;
  const int lane = threadIdx.x & 63;
  const int t = gw >> 6;
  const int b = gw & 63;
  const u16* hrow = hist + ((size_t)(t + 1) * B_ + b) * H_ + lane * 8;
  uint4 hv = *(const uint4*)hrow;
  float h[8];
  {
    u16x8 hu = __builtin_bit_cast(u16x8, hv);
    #pragma unroll
    for (int i = 0; i < 8; ++i) h[i] = bf2f(hu[i]);
  }
  float accs[O_];
  #pragma unroll
  for (int o = 0; o < O_; ++o) {
    const float* wr = fc_w + (size_t)o * H_ + lane * 8;
    float4 w0 = ((const float4*)wr)[0];
    float4 w1 = ((const float4*)wr)[1];
    accs[o] = h[0]*w0.x + h[1]*w0.y + h[2]*w0.z + h[3]*w0.w
            + h[4]*w1.x + h[5]*w1.y + h[6]*w1.z + h[7]*w1.w;
  }
  #pragma unroll
  for (int o = 0; o < O_; ++o)
    #pragma unroll
    for (int off = 32; off > 0; off >>= 1)
      accs[o] += __shfl_down(accs[o], off, 64);
  if (lane == 0) {
    #pragma unroll
    for (int o = 0; o < O_; ++o)
      out[((size_t)t * B_ + b) * O_ + o] = accs[o] + fc_b[o];
  }
}

extern "C" void kernel_launch(void* const* d_in, const int* in_sizes, int n_in,
                              void* d_out, int out_size, void* d_ws, size_t ws_size,
                              hipStream_t stream)
{
  (void)in_sizes; (void)n_in; (void)out_size; (void)ws_size;
  const float* x    = (const float*)d_in[0];
  const float* W_ih = (const float*)d_in[1];
  const float* W_hh = (const float*)d_in[2];
  const float* b_ih = (const float*)d_in[3];
  const float* b_hh = (const float*)d_in[4];
  const float* fc_w = (const float*)d_in[5];
  const float* fc_b = (const float*)d_in[6];
  float* out = (float*)d_out;

  u32* flags = (u32*)d_ws;                              // [8][64] = 2 KB
  u32* ex    = (u32*)((char*)d_ws + EX_OFF);            // [2][B][H] u32 = 256 KB
  u16* hist  = (u16*)((char*)d_ws + EX_OFF + 2 * BH * 4);

  // zero flags + both ex slots (slot0 = tag 0 = h_0 = 0; clears 0xAA poison)
  hipMemsetAsync(d_ws, 0, EX_OFF + 2 * BH * 4, stream);

  lstm_persistent<<<GRID_MAIN, BLOCK_MAIN, 0, stream>>>(
      x, W_ih, W_hh, b_ih, b_hh, out, flags, ex, hist);
  fc_kernel<<<(T_ * B_) / 4, 256, 0, stream>>>(hist, fc_w, fc_b, out);
}

// Round 12
// 2883.474 us; speedup vs baseline: 1.8140x; 1.6038x over previous
//
#include <hip/hip_runtime.h>
#include <stdint.h>

#define T_ 1024
#define B_ 64
#define I_ 256
#define H_ 512
#define O_ 5
#define NCHAIN 8
#define NB 8             // batches per chain
#define JW 16            // hidden columns per WG
#define GRID_MAIN 256    // 8 chains x 32 WGs (chain = wg&7, jslot = wg>>3)
#define BLOCK_MAIN 256
#define XBS 264          // xbuf row stride in u16 (R7 value)
#define EX_OFF 4096      // ex offset in ws (bytes)
#define BH (B_*H_)
#define TBO (T_*B_*O_)

typedef __bf16 bf16x8 __attribute__((ext_vector_type(8)));
typedef float floatx4 __attribute__((ext_vector_type(4)));
typedef unsigned short u16;
typedef unsigned short u16x8 __attribute__((ext_vector_type(8)));
typedef unsigned int u32;
typedef u32 u32x4 __attribute__((ext_vector_type(4)));

__device__ __forceinline__ u16 f2bf(float f) {
  unsigned int u = __float_as_uint(f);
  u += 0x7fffu + ((u >> 16) & 1u);   // RNE
  return (u16)(u >> 16);
}
__device__ __forceinline__ float bf2f(u16 v) {
  return __uint_as_float(((unsigned int)v) << 16);
}
// v_rcp_f32-based activations: removes 4 full-precision divides (~20+ cyc
// each) from the elementwise critical path; rcp err ~1e-6 << 1.65e-2 threshold.
__device__ __forceinline__ float sigmoid_f(float x) {
  return __builtin_amdgcn_rcpf(1.0f + __expf(-x));
}
__device__ __forceinline__ float tanh_f(float x) {
  return 2.0f * __builtin_amdgcn_rcpf(1.0f + __expf(-2.0f * x)) - 1.0f;
}

// ---- L3-coherent exchange primitives (sc0 sc1 = bypass L1/L2; Infinity
// Cache is the coherence point). R7 protocol frozen: cheap flag poll on tiny
// separate lines + ONE bf16 payload read, freshness via producer drain.
__device__ __forceinline__ u32 load_u32_l3(const u32* p) {
  u32 v;
  asm volatile("global_load_dword %0, %1, off sc0 sc1\n\ts_waitcnt vmcnt(0)"
               : "=v"(v) : "v"(p) : "memory");
  return v;
}
__device__ __forceinline__ void store_u32_l3(u32* p, u32 v) {
  asm volatile("global_store_dword %0, %1, off sc0 sc1" :: "v"(p), "v"(v) : "memory");
}

// bulk B-fragment loads (bf16 ex, one K-chunk = 32 h = 64 B/batch-row):
// issue all dwordx4 then ONE vmcnt (1 L3 round trip, not N).
__device__ __forceinline__ void load_h4_l3(const u16* p, u32x4* r) {
  asm volatile(
    "global_load_dwordx4 %0, %4, off sc0 sc1\n\t"
    "global_load_dwordx4 %1, %4, off offset:64 sc0 sc1\n\t"
    "global_load_dwordx4 %2, %4, off offset:128 sc0 sc1\n\t"
    "global_load_dwordx4 %3, %4, off offset:192 sc0 sc1\n\t"
    "s_waitcnt vmcnt(0)"
    : "=&v"(r[0]), "=&v"(r[1]), "=&v"(r[2]), "=&v"(r[3]) : "v"(p) : "memory");
}
__device__ __forceinline__ void load_h6_l3(const u16* p, u32x4* r) {
  asm volatile(
    "global_load_dwordx4 %0, %6, off sc0 sc1\n\t"
    "global_load_dwordx4 %1, %6, off offset:64 sc0 sc1\n\t"
    "global_load_dwordx4 %2, %6, off offset:128 sc0 sc1\n\t"
    "global_load_dwordx4 %3, %6, off offset:192 sc0 sc1\n\t"
    "global_load_dwordx4 %4, %6, off offset:256 sc0 sc1\n\t"
    "global_load_dwordx4 %5, %6, off offset:320 sc0 sc1\n\t"
    "s_waitcnt vmcnt(0)"
    : "=&v"(r[0]), "=&v"(r[1]), "=&v"(r[2]), "=&v"(r[3]), "=&v"(r[4]), "=&v"(r[5])
    : "v"(p) : "memory");
}

// stage bf16(x[ts]) slice (8 batches x 256) into LDS xbuf slot; u in [0,128)
__device__ __forceinline__ void stage_x(const float* __restrict__ xsrc,
                                        u16 (*xb)[XBS], int u) {
  #pragma unroll
  for (int i = 0; i < 2; ++i) {
    int cid = u + 128 * i;          // 256 chunks of 8 floats
    int b  = cid >> 5;
    int ko = (cid & 31) * 8;
    const float4* s = (const float4*)(xsrc + (size_t)b * I_ + ko);
    float4 f0 = s[0], f1 = s[1];
    u16x8 uu;
    uu[0]=f2bf(f0.x); uu[1]=f2bf(f0.y); uu[2]=f2bf(f0.z); uu[3]=f2bf(f0.w);
    uu[4]=f2bf(f1.x); uu[5]=f2bf(f1.y); uu[6]=f2bf(f1.z); uu[7]=f2bf(f1.w);
    *(u16x8*)&xb[b][ko] = uu;
  }
}

// Persistent LSTM, 8 chains x 32 WGs — R7 structure frozen. R12 deltas only:
// (1) per-wave flags stored PRE-barrier, each after its own s_waitcnt vmcnt(0)
//     drain (payload freshness preserved; flag just leaves earlier than R7's
//     post-barrier store), (2) no s_sleep in the flag poll, (3) rcp-based
//     activations. Payload lines still touched exactly once (R8/R9/R11 lesson).
__global__ __launch_bounds__(BLOCK_MAIN, 1)
void lstm_persistent(const float* __restrict__ x,
                     const float* __restrict__ W_ih,
                     const float* __restrict__ W_hh,
                     const float* __restrict__ b_ih,
                     const float* __restrict__ b_hh,
                     float* __restrict__ out,
                     u32* __restrict__ flags,   // [8][64]: flag[jslot*2 + wave]
                     u16* __restrict__ ex,      // [2][B_][H_] bf16
                     u16* __restrict__ hist)    // [(T_+1)][B_][H_] bf16
{
  __shared__ __align__(16) u16 xbuf[2][NB][XBS];
  __shared__ float part[4 * 4 * 16 * 17];       // [w][gate][j16][col(+pad)]

  const int tid  = threadIdx.x;
  const int wg   = blockIdx.x;
  const int w    = tid >> 6;        // wave id = K-quarter
  const int lane = tid & 63;
  const int q    = lane >> 4;
  const int n    = lane & 15;
  const int chain = wg & 7;
  const int jslot = wg >> 3;
  const int jbase = jslot * JW;
  const int bbase = chain * NB;

  // ---- W -> register A-fragments (A[m=lane&15][k=q*8+i]), once ----
  bf16x8 afrag[4][6];
  #pragma unroll
  for (int g = 0; g < 4; ++g) {
    #pragma unroll
    for (int kk = 0; kk < 6; ++kk) {
      const int kc  = w * 6 + kk;                 // K-chunk of 32
      const int row = g * H_ + jbase + n;         // gate row in [0,2048)
      const float* src;
      if (kc < 8) src = W_ih + (size_t)row * I_ + kc * 32 + q * 8;
      else        src = W_hh + (size_t)row * H_ + (kc - 8) * 32 + q * 8;
      float4 f0 = ((const float4*)src)[0];
      float4 f1 = ((const float4*)src)[1];
      bf16x8 a;
      a[0]=(__bf16)f0.x; a[1]=(__bf16)f0.y; a[2]=(__bf16)f0.z; a[3]=(__bf16)f0.w;
      a[4]=(__bf16)f1.x; a[5]=(__bf16)f1.y; a[6]=(__bf16)f1.z; a[7]=(__bf16)f1.w;
      afrag[g][kk] = a;
    }
  }

  // ---- elementwise identity: threads 0..127 own (eb in [0,8), ej in [0,16)) ----
  const int eb = tid >> 4;
  const int ej = tid & 15;
  float bias[4];
  float cval = 0.0f;
  if (tid < 128) {
    #pragma unroll
    for (int g = 0; g < 4; ++g)
      bias[g] = b_ih[g * H_ + jbase + ej] + b_hh[g * H_ + jbase + ej];
  }

  const int nx   = (w == 0) ? 6 : ((w == 1) ? 2 : 0);
  const int hoff = (w == 2) ? 128 : ((w == 3) ? 320 : 0);  // first h j-index
  // per-wave flag subsets: flag[jslot*2 + wv]; consumer needs both waves of
  // each producer WG covering its h K-slice:
  //   w1: jslots 0-7  -> flags 0-15 ; w2: jslots 8-19 -> 16-39 ; w3: 20-31 -> 40-63
  const int fbase = (w == 2) ? 16 : ((w == 3) ? 40 : 0);
  const int fcnt  = (w == 1) ? 16 : 24;
  u32* myflags = flags + chain * 64;
  const u32* fp = myflags + fbase + (lane % fcnt);
  const u16* hp0 = ex + (size_t)(bbase + (n & 7)) * H_ + hoff + q * 8;
  const u16* hp1 = hp0 + BH;

  // ---- pre-stage x_0 ----
  if (tid >= 128) stage_x(x + (size_t)bbase * I_, xbuf[0], tid - 128);
  __syncthreads();

  for (int t = 0; t < T_; ++t) {
    const int sr = t & 1, sw = (t + 1) & 1;

    bf16x8 bfrag[6];
    #pragma unroll
    for (int kk = 0; kk < 6; ++kk)
      if (kk < nx)
        bfrag[kk] = __builtin_bit_cast(bf16x8,
            *(const uint4*)&xbuf[sr][n & 7][(w * 6 + kk) * 32 + q * 8]);

    if (w > 0) {
      // flag wait: no sleep — the serialized L3 load paces the loop
      for (;;) {
        u32 f = load_u32_l3(fp);
        if (__all((int)(f >= (u32)t))) break;
      }
      // B-fragments straight from ex: one bulk L3 round trip, exactly once
      const u16* hp = sr ? hp1 : hp0;
      if (w == 1) {
        u32x4 r[4];
        load_h4_l3(hp, r);
        #pragma unroll
        for (int i = 0; i < 4; ++i)
          bfrag[2 + i] = __builtin_bit_cast(bf16x8, r[i]);
      } else {
        u32x4 r[6];
        load_h6_l3(hp, r);
        #pragma unroll
        for (int i = 0; i < 6; ++i)
          bfrag[i] = __builtin_bit_cast(bf16x8, r[i]);
      }
    }

    // ---- MFMA partial gates over this wave's K-quarter ----
    floatx4 acc[4] = {};
    #pragma unroll
    for (int kk = 0; kk < 6; ++kk) {
      #pragma unroll
      for (int g = 0; g < 4; ++g)
        acc[g] = __builtin_amdgcn_mfma_f32_16x16x32_bf16(afrag[g][kk], bfrag[kk], acc[g], 0, 0, 0);
    }

    // write partial C tiles (C: col=lane&15=batch, row=q*4+reg=j)
    #pragma unroll
    for (int g = 0; g < 4; ++g)
      #pragma unroll
      for (int r = 0; r < 4; ++r)
        part[((w * 4 + g) * 16 + (q * 4 + r)) * 17 + n] = acc[g][r];
    __syncthreads();

    if (tid < 128) {
      // ---- reduce 4 K-partials, gates -> c,h ; publish + per-wave flag ----
      float gate[4];
      #pragma unroll
      for (int g = 0; g < 4; ++g) {
        float s = bias[g];
        #pragma unroll
        for (int w2 = 0; w2 < 4; ++w2)
          s += part[((w2 * 4 + g) * 16 + ej) * 17 + eb];
        gate[g] = s;
      }
      const float ig = sigmoid_f(gate[0]);
      const float fg = sigmoid_f(gate[1]);
      const float gg = tanh_f(gate[2]);
      const float og = sigmoid_f(gate[3]);
      cval = fg * cval + ig * gg;
      const float hval = og * tanh_f(cval);
      const int bg = bbase + eb;
      const int jg = jbase + ej;
      // pair adjacent ej via shuffle; even thread stores the u32
      const u32 hb = (u32)f2bf(hval);
      const u32 other = __shfl_xor((int)hb, 1, 64);
      if ((tid & 1) == 0) {
        const u32 packed = hb | (other << 16);
        store_u32_l3((u32*)(ex + (size_t)sw * BH + (size_t)bg * H_ + jg), packed);
        *(u32*)(hist + (size_t)(t + 1) * BH + (size_t)bg * H_ + jg) = packed;
      }
      // drain own h stores, then this wave's flag — PRE-barrier publish
      asm volatile("s_waitcnt vmcnt(0)" ::: "memory");
      if (lane == 0)
        store_u32_l3(&myflags[jslot * 2 + w], (u32)(t + 1));
      if (t == T_ - 1) {
        out[TBO + (size_t)bg * H_ + jg]      = hval;   // h_T
        out[TBO + BH + (size_t)bg * H_ + jg] = cval;   // c_T
      }
    } else {
      // ---- waves 2,3: pre-stage x_{t+1} ----
      const int ts = (t + 1 < T_) ? (t + 1) : (T_ - 1);
      stage_x(x + ((size_t)ts * B_ + bbase) * I_, xbuf[sw], tid - 128);
    }
    __syncthreads();   // xbuf/part WAR only — publish already done
  }
}

// outputs[t,b,:] = h_t @ fc_w^T + fc_b ; one wave per (t,b) row
__global__ __launch_bounds__(256)
void fc_kernel(const u16* __restrict__ hist,
               const float* __restrict__ fc_w,
               const float* __restrict__ fc_b,
               float* __restrict__ out)
{
  const int gw   = (blockIdx.x * 256 + threadIdx.x) >> 6;
  const int lane = threadIdx.x & 63;
  const int t = gw >> 6;
  const int b = gw & 63;
  const u16* hrow = hist + ((size_t)(t + 1) * B_ + b) * H_ + lane * 8;
  uint4 hv = *(const uint4*)hrow;
  float h[8];
  {
    u16x8 hu = __builtin_bit_cast(u16x8, hv);
    #pragma unroll
    for (int i = 0; i < 8; ++i) h[i] = bf2f(hu[i]);
  }
  float accs[O_];
  #pragma unroll
  for (int o = 0; o < O_; ++o) {
    const float* wr = fc_w + (size_t)o * H_ + lane * 8;
    float4 w0 = ((const float4*)wr)[0];
    float4 w1 = ((const float4*)wr)[1];
    accs[o] = h[0]*w0.x + h[1]*w0.y + h[2]*w0.z + h[3]*w0.w
            + h[4]*w1.x + h[5]*w1.y + h[6]*w1.z + h[7]*w1.w;
  }
  #pragma unroll
  for (int o = 0; o < O_; ++o)
    #pragma unroll
    for (int off = 32; off > 0; off >>= 1)
      accs[o] += __shfl_down(accs[o], off, 64);
  if (lane == 0) {
    #pragma unroll
    for (int o = 0; o < O_; ++o)
      out[((size_t)t * B_ + b) * O_ + o] = accs[o] + fc_b[o];
  }
}

extern "C" void kernel_launch(void* const* d_in, const int* in_sizes, int n_in,
                              void* d_out, int out_size, void* d_ws, size_t ws_size,
                              hipStream_t stream)
{
  (void)in_sizes; (void)n_in; (void)out_size; (void)ws_size;
  const float* x    = (const float*)d_in[0];
  const float* W_ih = (const float*)d_in[1];
  const float* W_hh = (const float*)d_in[2];
  const float* b_ih = (const float*)d_in[3];
  const float* b_hh = (const float*)d_in[4];
  const float* fc_w = (const float*)d_in[5];
  const float* fc_b = (const float*)d_in[6];
  float* out = (float*)d_out;

  u32* flags = (u32*)d_ws;                              // [8][64] = 2 KB
  u16* ex    = (u16*)((char*)d_ws + EX_OFF);            // 2*BH bf16 = 128 KB
  u16* hist  = (u16*)((char*)d_ws + EX_OFF + 2 * BH * 2);

  // zero flags + both ex slots (slot0 = h_0 = 0; clears 0xAA poison)
  hipMemsetAsync(d_ws, 0, EX_OFF + 2 * BH * 2, stream);

  lstm_persistent<<<GRID_MAIN, BLOCK_MAIN, 0, stream>>>(
      x, W_ih, W_hh, b_ih, b_hh, out, flags, ex, hist);
  fc_kernel<<<(T_ * B_) / 4, 256, 0, stream>>>(hist, fc_w, fc_b, out);
}